// Round 10
// baseline (170.636 us; speedup 1.0000x reference)
//
#include <hip/hip_runtime.h>
#include <hip/hip_bf16.h>
#include <stdint.h>

#define Bn 8
#define Tn 2048
#define Cn 1024
#define Hn 128

typedef __attribute__((ext_vector_type(8))) short short8;
typedef __attribute__((ext_vector_type(4))) short short4v;
typedef __attribute__((ext_vector_type(4))) float f32x4;
typedef __attribute__((ext_vector_type(4))) int int4v;

static __device__ __forceinline__ unsigned short f2bf(float f) {
    union { float f; unsigned int u; } v; v.f = f;
    return (unsigned short)((v.u + 0x7FFFu + ((v.u >> 16) & 1u)) >> 16);
}
static __device__ __forceinline__ float bf2f(unsigned short h) {
    union { unsigned int u; float f; } v; v.u = ((unsigned int)h) << 16;
    return v.f;
}

// pack 8 f32 -> short8 bf16 (k-ascending), RNE via v_cvt_pk_bf16_f32 (T12/m240)
static __device__ __forceinline__ short8 cvt8(f32x4 a, f32x4 b) {
    union { unsigned int u[4]; short8 s; } r;
    asm("v_cvt_pk_bf16_f32 %0, %1, %2" : "=v"(r.u[0]) : "v"(a[0]), "v"(a[1]));
    asm("v_cvt_pk_bf16_f32 %0, %1, %2" : "=v"(r.u[1]) : "v"(a[2]), "v"(a[3]));
    asm("v_cvt_pk_bf16_f32 %0, %1, %2" : "=v"(r.u[2]) : "v"(b[0]), "v"(b[1]));
    asm("v_cvt_pk_bf16_f32 %0, %1, %2" : "=v"(r.u[3]) : "v"(b[2]), "v"(b[3]));
    return r.s;
}

// async 16B/lane global->LDS (dest = wave-uniform base + lane*16)
static __device__ __forceinline__ void async16(const void* g, void* l) {
    __builtin_amdgcn_global_load_lds(
        (const __attribute__((address_space(1))) unsigned int*)g,
        (__attribute__((address_space(3))) unsigned int*)l,
        16, 0, 0);
}

// K pre-scale: C^-0.5 * log2(e)  (softmax exp computed as exp2)
#define KSCALE 0.04508422f

#define BASE_BYTES (3u * Bn * Tn * Hn * 2u + 3u * Hn * Cn * 2u)   // 13,369,344
// bf16 partial slot: 2048 bf16 acc + 16 f32 ssum = 2080 shorts (4160 B)
#define SLOT_SH 2080
#define NBLK_FA 576   // 8 batches * 72 units
#define UPB_FA 72
#define CCHUNK 8

// ---------------- Kernel 0: W [1024][128] f32 -> WT [3][128][1024] bf16 ----
__global__ __launch_bounds__(256) void wt_prep(const float* __restrict__ Wk,
                                               const float* __restrict__ Wq,
                                               const float* __restrict__ Wv,
                                               unsigned short* __restrict__ WT) {
    int z = blockIdx.y;
    const float* W = (z == 0) ? Wk : (z == 1) ? Wq : Wv;
    unsigned short* wt = WT + (size_t)z * Hn * Cn;
    int o = blockIdx.x * 256 + threadIdx.x;
    int d = o >> 10;
    int k = o & (Cn - 1);
    wt[o] = f2bf(W[k * Hn + d]);
}

// ---------------- Kernel 1: proj13 (proj7 + K-phase rotation), KEPT -------
// r9: rotation confirmed the W-broadcast hot-bank theory: 44 -> 40us.
__global__ __launch_bounds__(256) void proj13(const float* __restrict__ x,
                                              const unsigned short* __restrict__ WTb,
                                              unsigned short* __restrict__ Kb,
                                              unsigned short* __restrict__ Qb,
                                              unsigned short* __restrict__ VT) {
    __shared__ __align__(16) unsigned short Bsm[2][128 * 64];  // 16KB/buf, swizzled
    __shared__ __align__(16) unsigned short Asm[2][64 * 64];   // 8KB/buf, swizzled
    int tid = threadIdx.x;
    int lane = tid & 63, w = tid >> 6;
    int lr = lane & 15, lg = lane >> 4;
    int wm = w >> 1, wn = w & 1;

    // XCD-chunked swizzle (768 % 8 == 0)
    int u = ((int)(blockIdx.x & 7)) * 96 + ((int)blockIdx.x >> 3);
    int rg = u / 3, cg = u - rg * 3;
    int r0 = rg * 64;
    const unsigned short* WTz = WTb + (size_t)cg * Hn * Cn;
    int kph = u & 15;                       // K-phase: spreads W reads across L2

    // B staging: wave w stages chunks w*4..w*4+3; chunk = 1KB = 8 rows x 128B.
    int brow_in = lane >> 3;
    int bslot = (lane & 7) ^ brow_in;         // pre-swizzled 16B slot
    const unsigned short* bsrc[4];
    #pragma unroll
    for (int i = 0; i < 4; ++i) {
        int ch = w * 4 + i;
        bsrc[i] = WTz + (size_t)(ch * 8 + brow_in) * Cn + bslot * 8;
    }

    // A staging: thread t -> row t>>2, k-quarter t&3 (16 f32 = 64B).
    int ar_s = tid >> 2;
    int ah = tid & 3;
    const float* axp = x + (size_t)(r0 + ar_s) * Cn + ah * 16;
    int asw = (ar_s & 7) << 4;
    unsigned int awb0 = ar_s * 128 + ((ah * 32) ^ asw);
    unsigned int awb1 = ar_s * 128 + ((ah * 32 + 16) ^ asw);

    f32x4 a_r[4];
    auto LOADA = [&](int k0) {
        #pragma unroll
        for (int i = 0; i < 4; ++i)
            a_r[i] = *(const f32x4*)(axp + k0 + i * 4);
    };
    auto STAGEB = [&](int bb, int k0) {
        #pragma unroll
        for (int i = 0; i < 4; ++i)
            async16(bsrc[i] + k0, &Bsm[bb][(w * 4 + i) * 512]);
    };
    auto WRITEA = [&](int bb) {
        short8 w0 = cvt8(a_r[0], a_r[1]);
        short8 w1 = cvt8(a_r[2], a_r[3]);
        char* base = (char*)&Asm[bb][0];
        *(short8*)(base + awb0) = w0;
        *(short8*)(base + awb1) = w1;
    };

    f32x4 acc[2][4] = {};
    int k0s = kph << 6;                     // step 0 (rotated)
    LOADA(k0s);
    STAGEB(0, k0s);
    WRITEA(0);
    __syncthreads();
    int cur = 0;
    for (int ks = 0; ks < 16; ++ks) {
        if (ks < 15) {
            int k0n = (((ks + 1 + kph) & 15) << 6);   // rotated next K-chunk
            LOADA(k0n);
            STAGEB(cur ^ 1, k0n);
        }
        const char* ab = (const char*)&Asm[cur][0];
        const char* bbp = (const char*)&Bsm[cur][0];
        #pragma unroll
        for (int kk = 0; kk < 2; ++kk) {
            short8 af[2], bf[4];
            #pragma unroll
            for (int m = 0; m < 2; ++m) {
                int row = wm * 32 + m * 16 + lr;
                af[m] = *(const short8*)(ab + row * 128 + ((kk * 64 + lg * 16) ^ ((row & 7) << 4)));
            }
            #pragma unroll
            for (int c = 0; c < 4; ++c) {
                int row = wn * 64 + c * 16 + lr;
                bf[c] = *(const short8*)(bbp + row * 128 + ((kk * 64 + lg * 16) ^ ((row & 7) << 4)));
            }
            #pragma unroll
            for (int m = 0; m < 2; ++m)
                #pragma unroll
                for (int c = 0; c < 4; ++c)
                    acc[m][c] = __builtin_amdgcn_mfma_f32_16x16x32_bf16(af[m], bf[c], acc[m][c], 0, 0, 0);
        }
        if (ks < 15) WRITEA(cur ^ 1);
        __syncthreads();
        cur ^= 1;
    }

    if (cg == 2) {
        int bb = r0 >> 11;
        int tb = r0 & 2047;
        #pragma unroll
        for (int m = 0; m < 2; ++m)
            #pragma unroll
            for (int c = 0; c < 4; ++c) {
                int d = wn * 64 + c * 16 + lr;
                int t = tb + wm * 32 + m * 16 + lg * 4;
                short4v pv;
                pv[0] = (short)f2bf(acc[m][c][0]);
                pv[1] = (short)f2bf(acc[m][c][1]);
                pv[2] = (short)f2bf(acc[m][c][2]);
                pv[3] = (short)f2bf(acc[m][c][3]);
                *(short4v*)(VT + ((size_t)(bb * Hn + d) << 11) + t) = pv;
            }
    } else {
        unsigned short* outp = (cg == 0) ? Kb : Qb;
        float sc = (cg == 0) ? KSCALE : 1.0f;
        #pragma unroll
        for (int m = 0; m < 2; ++m)
            #pragma unroll
            for (int c = 0; c < 4; ++c) {
                int d = wn * 64 + c * 16 + lr;
                #pragma unroll
                for (int r = 0; r < 4; ++r) {
                    int i = r0 + wm * 32 + m * 16 + lg * 4 + r;
                    outp[(size_t)i * Hn + d] = f2bf(acc[m][c][r] * sc);
                }
            }
    }
}

// ---------------- Kernel 2a: attention partials, DE-STAGED (fattn9) -------
// m169 precedent: Q/V per batch = 512KB each, L2-resident on their XCD
// (batch-contiguous swizzle). LDS-staging + per-tile __syncthreads was pure
// overhead -> read Q/V fragments straight from L2 per tile. ZERO barriers:
// each wave is an independent flash-attn streamer (18 waves/CU of TLP).
// pbuf is wave-private (no barrier needed). setprio around MFMA (m191).
// Unit decode, partial layout, accP format identical to fattn8 -> combine3
// unchanged.
__global__ __launch_bounds__(512) void fattn9(const unsigned short* __restrict__ Kb,
                                              const unsigned short* __restrict__ Qb,
                                              const unsigned short* __restrict__ VT,
                                              unsigned short* __restrict__ accP) {
    __shared__ __align__(16) unsigned short pbuf[8][16][48];
    int tid = threadIdx.x, lane = tid & 63, w = tid >> 6;
    int lr = lane & 15, lg = lane >> 4;

    // batch-contiguous XCD swizzle: XCD i -> units of batch i (L2-resident)
    int cpx = gridDim.x >> 3;
    int u = ((int)blockIdx.x & 7) * cpx + ((int)blockIdx.x >> 3);
    int b = u / UPB_FA, rem = u - b * UPB_FA;
    int g = 0, p = 0;
    for (;;) {
        int P = (4 * g + 4 + CCHUNK - 1) / CCHUNK;
        if (rem < P) { p = rem; break; }
        rem -= P; ++g;
    }
    int nt = 4 * g + 4;
    int P = (nt + CCHUNK - 1) / CCHUNK;
    int q = nt / P, r = nt % P;
    int begin = p * q + (p < r ? p : r);
    int size = q + (p < r ? 1 : 0);

    int i0 = g * 128 + w * 16;
    int tmax = (i0 + 15) >> 5;
    const unsigned short* kb = Kb + (size_t)b * Tn * Hn;
    const unsigned short* qb = Qb + (size_t)b * Tn * Hn;
    const unsigned short* vt = VT + (size_t)b * Hn * Tn;

    short8 kf[4];
    #pragma unroll
    for (int kk = 0; kk < 4; ++kk)
        kf[kk] = *(const short8*)(kb + (size_t)(i0 + lr) * Hn + kk * 32 + lg * 8);

    f32x4 acc[8] = {};
    float ssum[4] = {0.f, 0.f, 0.f, 0.f};

    for (int ti = 0; ti < size; ++ti) {
        int tt = begin + ti;
        if (tt > tmax) break;               // tiles ascend; rest are masked out
        int j0 = tt * 32;
        f32x4 sa0 = {}, sa1 = {};
        __builtin_amdgcn_s_setprio(1);
        #pragma unroll
        for (int kk = 0; kk < 4; ++kk) {
            short8 q0 = *(const short8*)(qb + (size_t)(j0 + lr) * Hn + kk * 32 + lg * 8);
            sa0 = __builtin_amdgcn_mfma_f32_16x16x32_bf16(kf[kk], q0, sa0, 0, 0, 0);
        }
        #pragma unroll
        for (int kk = 0; kk < 4; ++kk) {
            short8 q1 = *(const short8*)(qb + (size_t)(j0 + 16 + lr) * Hn + kk * 32 + lg * 8);
            sa1 = __builtin_amdgcn_mfma_f32_16x16x32_bf16(kf[kk], q1, sa1, 0, 0, 0);
        }
        __builtin_amdgcn_s_setprio(0);
        bool needmask = (j0 + 31 > i0);
        #pragma unroll
        for (int rr = 0; rr < 4; ++rr) {
            float v0 = sa0[rr], v1 = sa1[rr];
            if (needmask) {
                int i = i0 + lg * 4 + rr;
                if (j0 + lr > i)      v0 = -1e30f;
                if (j0 + 16 + lr > i) v1 = -1e30f;
            }
            float p0 = __builtin_amdgcn_exp2f(v0);
            float p1 = __builtin_amdgcn_exp2f(v1);
            ssum[rr] += p0 + p1;
            pbuf[w][lg * 4 + rr][lr] = f2bf(p0);
            pbuf[w][lg * 4 + rr][16 + lr] = f2bf(p1);
        }
        short8 pf = *(const short8*)(&pbuf[w][lr][lg * 8]);
        __builtin_amdgcn_s_setprio(1);
        #pragma unroll
        for (int n = 0; n < 8; ++n) {
            short8 vf = *(const short8*)(vt + (size_t)(n * 16 + lr) * Tn + j0 + lg * 8);
            acc[n] = __builtin_amdgcn_mfma_f32_16x16x32_bf16(pf, vf, acc[n], 0, 0, 0);
        }
        __builtin_amdgcn_s_setprio(0);
    }

    // store bf16 partial (reg-native layout), 8B/lane per n
    unsigned short* dst = accP + (size_t)u * 8 * SLOT_SH + (size_t)w * SLOT_SH;
    #pragma unroll
    for (int n = 0; n < 8; ++n) {
        short4v pv;
        pv[0] = (short)f2bf(acc[n][0]);
        pv[1] = (short)f2bf(acc[n][1]);
        pv[2] = (short)f2bf(acc[n][2]);
        pv[3] = (short)f2bf(acc[n][3]);
        *(short4v*)(dst + n * 256 + lane * 4) = pv;
    }
    #pragma unroll
    for (int rr = 0; rr < 4; ++rr) {
        float s = ssum[rr];
        s += __shfl_xor(s, 1);
        s += __shfl_xor(s, 2);
        s += __shfl_xor(s, 4);
        s += __shfl_xor(s, 8);
        if (lr == 0) ((float*)(dst + 2048))[lg * 4 + rr] = s;
    }
}

// ---------------- Kernel 2b: combine bf16 partials -> out ------------------
__global__ __launch_bounds__(256) void combine3(const unsigned short* __restrict__ accP,
                                                float* __restrict__ out) {
    int cpx = gridDim.x >> 3;
    int bidx = ((int)blockIdx.x & 7) * cpx + ((int)blockIdx.x >> 3);
    int b = bidx >> 7, tile = bidx & 127;          // tile = g*8 + w
    int g = tile >> 3, wq = tile & 7;
    int ub = b * UPB_FA;
    for (int gg = 0; gg < g; ++gg) ub += (4 * gg + 4 + CCHUNK - 1) / CCHUNK;
    int nt = 4 * g + 4;
    int P = (nt + CCHUNK - 1) / CCHUNK;

    int tid = threadIdx.x;
    int row = tid >> 4;
    int c8 = (tid & 15) * 8;

    const unsigned short* base = accP + ((size_t)ub * 8 + wq) * SLOT_SH;
    const size_t pstr = (size_t)8 * SLOT_SH;
    float den = 0.f;
    for (int pp = 0; pp < P; ++pp) den += ((const float*)(base + pp * pstr + 2048))[row];
    float inv = 1.0f / den;

    int lgg = row >> 2, r4 = row & 3;
    float ov[8];
    #pragma unroll
    for (int cc = 0; cc < 8; ++cc) {
        int col = c8 + cc;
        int n = col >> 4, lrr = col & 15;
        int flat = n * 256 + (lgg * 16 + lrr) * 4 + r4;
        float s = 0.f;
        for (int pp = 0; pp < P; ++pp) s += bf2f(base[pp * pstr + flat]);
        ov[cc] = s * inv;
    }
    float* op = out + ((size_t)(b * Tn + tile * 16 + row)) * Hn + c8;
    *(f32x4*)op       = f32x4{ov[0], ov[1], ov[2], ov[3]};
    *(f32x4*)(op + 4) = f32x4{ov[4], ov[5], ov[6], ov[7]};
}

// ---------------- Fallback attention (round-2, in-block kv split) ----------
__global__ __launch_bounds__(256) void attn(const unsigned short* __restrict__ Kb,
                                            const unsigned short* __restrict__ Qb,
                                            const unsigned short* __restrict__ VT,
                                            float* __restrict__ out) {
    __shared__ unsigned short pbuf[4][16][32];
    __shared__ __align__(16) float accbuf[4][16][132];
    __shared__ float ssbuf[4][16];
    int lane = threadIdx.x & 63;
    int w = threadIdx.x >> 6;
    int b = blockIdx.y;
    int xb = blockIdx.x;
    int tile = (xb & 1) ? (127 - (xb >> 1)) : (xb >> 1);
    int i0 = tile * 16;
    int lr = lane & 15, lg = lane >> 4;

    const unsigned short* kb = Kb + (size_t)b * Tn * Hn;
    const unsigned short* qb = Qb + (size_t)b * Tn * Hn;
    const unsigned short* vt = VT + (size_t)b * Hn * Tn;

    short8 kf[4];
    #pragma unroll
    for (int kk = 0; kk < 4; ++kk)
        kf[kk] = *(const short8*)(kb + (size_t)(i0 + lr) * Hn + kk * 32 + lg * 8);

    f32x4 acc[8] = {};
    float ssum[4] = {0.f, 0.f, 0.f, 0.f};

    int nt = (i0 + 15) / 32 + 1;
    for (int tt = w; tt < nt; tt += 4) {
        int j0 = tt * 32;
        f32x4 sa0 = {}, sa1 = {};
        #pragma unroll
        for (int kk = 0; kk < 4; ++kk) {
            short8 q0 = *(const short8*)(qb + (size_t)(j0 + lr) * Hn + kk * 32 + lg * 8);
            sa0 = __builtin_amdgcn_mfma_f32_16x16x32_bf16(kf[kk], q0, sa0, 0, 0, 0);
        }
        #pragma unroll
        for (int kk = 0; kk < 4; ++kk) {
            short8 q1 = *(const short8*)(qb + (size_t)(j0 + 16 + lr) * Hn + kk * 32 + lg * 8);
            sa1 = __builtin_amdgcn_mfma_f32_16x16x32_bf16(kf[kk], q1, sa1, 0, 0, 0);
        }
        bool needmask = (j0 + 31 > i0);
        #pragma unroll
        for (int r = 0; r < 4; ++r) {
            float v0 = sa0[r], v1 = sa1[r];
            if (needmask) {
                int i = i0 + lg * 4 + r;
                if (j0 + lr > i)      v0 = -1e30f;
                if (j0 + 16 + lr > i) v1 = -1e30f;
            }
            float p0 = __builtin_amdgcn_exp2f(v0);
            float p1 = __builtin_amdgcn_exp2f(v1);
            ssum[r] += p0 + p1;
            pbuf[w][lg * 4 + r][lr] = f2bf(p0);
            pbuf[w][lg * 4 + r][16 + lr] = f2bf(p1);
        }
        short8 pf = *(const short8*)(&pbuf[w][lr][lg * 8]);
        #pragma unroll
        for (int n = 0; n < 8; ++n) {
            short8 vf = *(const short8*)(vt + (size_t)(n * 16 + lr) * Tn + j0 + lg * 8);
            acc[n] = __builtin_amdgcn_mfma_f32_16x16x32_bf16(pf, vf, acc[n], 0, 0, 0);
        }
    }

    #pragma unroll
    for (int r = 0; r < 4; ++r) {
        float s = ssum[r];
        s += __shfl_xor(s, 1);
        s += __shfl_xor(s, 2);
        s += __shfl_xor(s, 4);
        s += __shfl_xor(s, 8);
        if (lr == 0) ssbuf[w][lg * 4 + r] = s;
    }
    #pragma unroll
    for (int n = 0; n < 8; ++n)
        #pragma unroll
        for (int r = 0; r < 4; ++r)
            accbuf[w][lg * 4 + r][n * 16 + lr] = acc[n][r];
    __syncthreads();

    int row = threadIdx.x >> 5;
    int col = (threadIdx.x & 31) * 4;
    #pragma unroll
    for (int h = 0; h < 2; ++h) {
        int rr = row + h * 8;
        f32x4 s = *(const f32x4*)(&accbuf[0][rr][col]);
        #pragma unroll
        for (int ww = 1; ww < 4; ++ww) {
            f32x4 t = *(const f32x4*)(&accbuf[ww][rr][col]);
            s[0] += t[0]; s[1] += t[1]; s[2] += t[2]; s[3] += t[3];
        }
        float den = ssbuf[0][rr] + ssbuf[1][rr] + ssbuf[2][rr] + ssbuf[3][rr];
        float inv = 1.0f / den;
        s[0] *= inv; s[1] *= inv; s[2] *= inv; s[3] *= inv;
        *(f32x4*)(&out[((size_t)(b * Tn + i0 + rr)) * Hn + col]) = s;
    }
}

extern "C" void kernel_launch(void* const* d_in, const int* in_sizes, int n_in,
                              void* d_out, int out_size, void* d_ws, size_t ws_size,
                              hipStream_t stream) {
    const float* x  = (const float*)d_in[0];
    const float* Wk = (const float*)d_in[1];
    const float* Wq = (const float*)d_in[2];
    const float* Wv = (const float*)d_in[3];

    unsigned short* Kb = (unsigned short*)d_ws;                 // [8][2048][128] bf16 (pre-scaled)
    unsigned short* Qb = Kb + (size_t)Bn * Tn * Hn;             // [8][2048][128] bf16
    unsigned short* VT = Qb + (size_t)Bn * Tn * Hn;             // [8][128][2048] bf16
    unsigned short* WT = VT + (size_t)Bn * Tn * Hn;             // [3][128][1024] bf16
    unsigned short* accP = (unsigned short*)((char*)d_ws + BASE_BYTES);

    wt_prep<<<dim3(512, 3), 256, 0, stream>>>(Wk, Wq, Wv, WT);
    proj13<<<dim3(768), 256, 0, stream>>>(x, WT, Kb, Qb, VT);

    const size_t need = (size_t)BASE_BYTES + (size_t)NBLK_FA * 8 * SLOT_SH * 2;  // ~32.5 MB
    if (ws_size >= need) {
        fattn9<<<dim3(NBLK_FA), 512, 0, stream>>>(Kb, Qb, VT, accP);
        combine3<<<dim3(1024), 256, 0, stream>>>(accP, (float*)d_out);
    } else {
        attn<<<dim3(128, 8), 256, 0, stream>>>(Kb, Qb, VT, (float*)d_out);
    }
}

// Round 11
// 88.752 us; speedup vs baseline: 1.9226x; 1.9226x over previous
//
#include <hip/hip_runtime.h>
#include <hip/hip_bf16.h>
#include <stdint.h>

#define Bn 8
#define Tn 2048
#define Cn 1024
#define Hn 128

typedef __attribute__((ext_vector_type(8))) short short8;
typedef __attribute__((ext_vector_type(4))) short short4v;
typedef __attribute__((ext_vector_type(4))) float f32x4;
typedef __attribute__((ext_vector_type(4))) int int4v;

static __device__ __forceinline__ unsigned short f2bf(float f) {
    union { float f; unsigned int u; } v; v.f = f;
    return (unsigned short)((v.u + 0x7FFFu + ((v.u >> 16) & 1u)) >> 16);
}
static __device__ __forceinline__ float bf2f(unsigned short h) {
    union { unsigned int u; float f; } v; v.u = ((unsigned int)h) << 16;
    return v.f;
}

// pack 8 f32 -> short8 bf16 (k-ascending), RNE via v_cvt_pk_bf16_f32 (T12/m240)
static __device__ __forceinline__ short8 cvt8(f32x4 a, f32x4 b) {
    union { unsigned int u[4]; short8 s; } r;
    asm("v_cvt_pk_bf16_f32 %0, %1, %2" : "=v"(r.u[0]) : "v"(a[0]), "v"(a[1]));
    asm("v_cvt_pk_bf16_f32 %0, %1, %2" : "=v"(r.u[1]) : "v"(a[2]), "v"(a[3]));
    asm("v_cvt_pk_bf16_f32 %0, %1, %2" : "=v"(r.u[2]) : "v"(b[0]), "v"(b[1]));
    asm("v_cvt_pk_bf16_f32 %0, %1, %2" : "=v"(r.u[3]) : "v"(b[2]), "v"(b[3]));
    return r.s;
}

// async 16B/lane global->LDS (dest = wave-uniform base + lane*16)
static __device__ __forceinline__ void async16(const void* g, void* l) {
    __builtin_amdgcn_global_load_lds(
        (const __attribute__((address_space(1))) unsigned int*)g,
        (__attribute__((address_space(3))) unsigned int*)l,
        16, 0, 0);
}

// K pre-scale: C^-0.5 * log2(e)  (softmax exp computed as exp2)
#define KSCALE 0.04508422f

#define BASE_BYTES (3u * Bn * Tn * Hn * 2u + 3u * Hn * Cn * 2u)   // 13,369,344
// bf16 partial slot: 2048 bf16 acc + 16 f32 ssum = 2080 shorts (4160 B)
#define SLOT_SH 2080
#define NBLK_FA 576   // 8 batches * 72 units
#define UPB_FA 72
#define CCHUNK 8

// ---------------- Kernel 0: W [1024][128] f32 -> WT [3][128][1024] bf16 ----
__global__ __launch_bounds__(256) void wt_prep(const float* __restrict__ Wk,
                                               const float* __restrict__ Wq,
                                               const float* __restrict__ Wv,
                                               unsigned short* __restrict__ WT) {
    int z = blockIdx.y;
    const float* W = (z == 0) ? Wk : (z == 1) ? Wq : Wv;
    unsigned short* wt = WT + (size_t)z * Hn * Cn;
    int o = blockIdx.x * 256 + threadIdx.x;
    int d = o >> 10;
    int k = o & (Cn - 1);
    wt[o] = f2bf(W[k * Hn + d]);
}

// ---------------- Kernel 1: proj14 = x-once + counted-vmcnt + rotation ----
// Service-rate model (r7 ablation + r9 rotation): staged demand serviced at
// ~9 TB/s regardless of schedule. proj13 demand = 384MB (x read 3x) = 40us.
// proj14 minimizes demand: tile 64 rows x 384 cols (K|Q|V fused, x ONCE) ->
// demand 64+192 = 256MB -> ~29us IF the pipe stays full at 1 block/CU.
// That's what the proj9-PROVEN 3-buffer / stage-2-ahead / counted-vmcnt(4)
// schedule provides (loads stay in flight across barriers; no co-resident
// block needed). kph rotation (r9, +10%) spreads the W broadcast.
// 8 waves (2M x 4N, wave 32x96), BK=32, 32 steps, 12 MFMA/wave/step.
// LDS: B 3x24KB + A(f32) 3x8KB = 96KB. Swizzles = proj9's (conflict-free).
__global__ __launch_bounds__(512) void proj14(const float* __restrict__ x,
                                              const unsigned short* __restrict__ WTb,
                                              unsigned short* __restrict__ Kb,
                                              unsigned short* __restrict__ Qb,
                                              unsigned short* __restrict__ VT) {
    __shared__ __align__(16) unsigned short Bsm[3][384 * 32];  // 3 x 24KB
    __shared__ __align__(16) float Asm[3][64 * 32];            // 3 x 8KB
    int tid = threadIdx.x;
    int lane = tid & 63, w = tid >> 6;
    int lr = lane & 15, lg = lane >> 4;
    int wm = w >> 2, wn = w & 3;

    // XCD swizzle: 256 blocks -> 32 contiguous row-groups per XCD
    int u = ((int)(blockIdx.x & 7)) * 32 + ((int)blockIdx.x >> 3);
    int r0 = u * 64;
    int kph = u & 31;                      // K-phase rotation (r9-proven)

    // B staging: 24 chunks/buf (1KB = 16 rows x 64B); wave w stages 3 chunks.
    // Source 16B-slot pre-swizzled s^((row>>1)&3) (proj9 involution).
    const unsigned short* bsrc[3];
    #pragma unroll
    for (int i = 0; i < 3; ++i) {
        int brow = (w * 3 + i) * 16 + (lane >> 2);
        int bslot = (lane & 3) ^ ((brow >> 1) & 3);
        bsrc[i] = WTb + (size_t)brow * Cn + bslot * 8;
    }
    // A staging: 8 chunks/buf (1KB = 8 rows x 128B f32); wave w stages chunk w.
    // Source slot pre-swizzled s^(row&7) (proj9 involution).
    int arow = w * 8 + (lane >> 3);
    int aslot = (lane & 7) ^ (arow & 7);
    const float* asrc = x + (size_t)(r0 + arow) * Cn + aslot * 4;

    auto STAGE = [&](int bb, int k0) {   // 4 vm ops per wave, uniform
        #pragma unroll
        for (int i = 0; i < 3; ++i)
            async16(bsrc[i] + k0, &Bsm[bb][(w * 3 + i) * 512]);
        async16(asrc + k0, &Asm[bb][w * 256]);
    };
    auto K0 = [&](int ks) { return ((ks + kph) & 31) << 5; };

    f32x4 acc[2][6] = {};
    STAGE(0, K0(0));
    STAGE(1, K0(1));
    int cur = 0;
    for (int ks = 0; ks < 32; ++ks) {
        // outstanding: STAGE(ks) [oldest 4] + STAGE(ks+1) [newest 4];
        // wait own-wave oldest 4 done, keep newest 4 in flight (proj9 scheme).
        if (ks < 31) asm volatile("s_waitcnt vmcnt(4)" ::: "memory");
        else         asm volatile("s_waitcnt vmcnt(0)" ::: "memory");
        __builtin_amdgcn_s_barrier();
        __builtin_amdgcn_sched_barrier(0);
        if (ks < 30) {
            int nb = cur + 2; if (nb >= 3) nb -= 3;   // buf read at ks-1: free
            STAGE(nb, K0(ks + 2));
        }
        const char* ab = (const char*)&Asm[cur][0];
        const char* bbp = (const char*)&Bsm[cur][0];
        short8 af[2], bf[6];
        #pragma unroll
        for (int m = 0; m < 2; ++m) {
            int row = wm * 32 + m * 16 + lr;
            const char* abase = ab + row * 128;
            f32x4 a0 = *(const f32x4*)(abase + (((lg * 2)     ^ (row & 7)) << 4));
            f32x4 a1 = *(const f32x4*)(abase + (((lg * 2 + 1) ^ (row & 7)) << 4));
            af[m] = cvt8(a0, a1);
        }
        #pragma unroll
        for (int c = 0; c < 6; ++c) {
            int row = wn * 96 + c * 16 + lr;
            bf[c] = *(const short8*)(bbp + row * 64 + ((lg ^ ((row >> 1) & 3)) << 4));
        }
        #pragma unroll
        for (int m = 0; m < 2; ++m)
            #pragma unroll
            for (int c = 0; c < 6; ++c)
                acc[m][c] = __builtin_amdgcn_mfma_f32_16x16x32_bf16(af[m], bf[c], acc[m][c], 0, 0, 0);
        ++cur; if (cur == 3) cur = 0;
    }

    int bb = r0 >> 11;
    int tb = r0 & 2047;
    #pragma unroll
    for (int m = 0; m < 2; ++m)
        #pragma unroll
        for (int c = 0; c < 6; ++c) {
            int col0 = wn * 96 + c * 16;        // 16-aligned, never crosses 128
            int z = col0 >> 7;
            int d = (col0 & 127) + lr;
            if (z == 2) {
                int t = tb + wm * 32 + m * 16 + lg * 4;
                short4v pv;
                pv[0] = (short)f2bf(acc[m][c][0]);
                pv[1] = (short)f2bf(acc[m][c][1]);
                pv[2] = (short)f2bf(acc[m][c][2]);
                pv[3] = (short)f2bf(acc[m][c][3]);
                *(short4v*)(VT + ((size_t)(bb * Hn + d) << 11) + t) = pv;
            } else {
                unsigned short* outp = (z == 0) ? Kb : Qb;
                float sc = (z == 0) ? KSCALE : 1.0f;
                #pragma unroll
                for (int r = 0; r < 4; ++r) {
                    int i = r0 + wm * 32 + m * 16 + lg * 4 + r;
                    outp[(size_t)i * Hn + d] = f2bf(acc[m][c][r] * sc);
                }
            }
        }
}

// ---------------- Kernel 2a: attention partials (fattn8, RESTORED) --------
// r10: de-staging was -84us (L2 request amplification). LDS staging shared
// by 8 waves is load-bearing. This is the round-9 known-good kernel.
__global__ __launch_bounds__(512) void fattn8(const unsigned short* __restrict__ Kb,
                                              const unsigned short* __restrict__ Qb,
                                              const unsigned short* __restrict__ VT,
                                              unsigned short* __restrict__ accP) {
    __shared__ __align__(16) unsigned short Ksm[2][32 * 128];   // kv rows x d, swz (row&7)<<4
    __shared__ __align__(16) unsigned short Vsm[2][128 * 32];   // d rows x t, dense
    __shared__ __align__(16) unsigned short pbuf[8][16][48];
    int tid = threadIdx.x, lane = tid & 63, w = tid >> 6;
    int lr = lane & 15, lg = lane >> 4;

    int cpx = gridDim.x >> 3;
    int u = ((int)blockIdx.x & 7) * cpx + ((int)blockIdx.x >> 3);
    int b = u / UPB_FA, rem = u - b * UPB_FA;
    int g = 0, p = 0;
    for (;;) {
        int P = (4 * g + 4 + CCHUNK - 1) / CCHUNK;
        if (rem < P) { p = rem; break; }
        rem -= P; ++g;
    }
    int nt = 4 * g + 4;
    int P = (nt + CCHUNK - 1) / CCHUNK;
    int q = nt / P, r = nt % P;
    int begin = p * q + (p < r ? p : r);
    int size = q + (p < r ? 1 : 0);

    int i0 = g * 128 + w * 16;
    int tmax = (i0 + 15) >> 5;
    const unsigned short* kb = Kb + (size_t)b * Tn * Hn;
    const unsigned short* qb = Qb + (size_t)b * Tn * Hn;
    const unsigned short* vt = VT + (size_t)b * Hn * Tn;

    short8 kf[4];
    #pragma unroll
    for (int kk = 0; kk < 4; ++kk)
        kf[kk] = *(const short8*)(kb + (size_t)(i0 + lr) * Hn + kk * 32 + lg * 8);

    int krow = tid >> 4, kcol = (tid & 15) * 8;    // K stage: 32 rows x 128 d
    int vrow = tid >> 2, vcol = (tid & 3) * 8;     // V stage: 128 rows x 32 t
    int4v kreg, vreg;
    auto LOADT = [&](int tt) {
        int j0 = tt * 32;
        kreg = *(const int4v*)(qb + (size_t)(j0 + krow) * Hn + kcol);
        vreg = *(const int4v*)(vt + (size_t)vrow * Tn + j0 + vcol);
    };
    auto WRITET = [&](int bb) {
        *(int4v*)((char*)&Ksm[bb][0] + krow * 256 + ((kcol * 2) ^ ((krow & 7) << 4))) = kreg;
        *(int4v*)((char*)&Vsm[bb][0] + vrow * 64 + vcol * 2) = vreg;
    };

    f32x4 acc[8] = {};
    float ssum[4] = {0.f, 0.f, 0.f, 0.f};

    LOADT(begin);
    WRITET(0);
    __syncthreads();
    int cur = 0;
    for (int ti = 0; ti < size; ++ti) {
        int tt = begin + ti;
        if (ti + 1 < size) LOADT(tt + 1);
        if (tt <= tmax) {
            int j0 = tt * 32;
            const char* kbp = (const char*)&Ksm[cur][0];
            const char* vbp = (const char*)&Vsm[cur][0];
            f32x4 sa0 = {}, sa1 = {};
            #pragma unroll
            for (int kk = 0; kk < 4; ++kk) {
                int row = lr;
                short8 qf = *(const short8*)(kbp + row * 256 + (((kk * 64) + lg * 16) ^ ((row & 7) << 4)));
                sa0 = __builtin_amdgcn_mfma_f32_16x16x32_bf16(kf[kk], qf, sa0, 0, 0, 0);
            }
            #pragma unroll
            for (int kk = 0; kk < 4; ++kk) {
                int row = 16 + lr;
                short8 qf = *(const short8*)(kbp + row * 256 + (((kk * 64) + lg * 16) ^ ((row & 7) << 4)));
                sa1 = __builtin_amdgcn_mfma_f32_16x16x32_bf16(kf[kk], qf, sa1, 0, 0, 0);
            }
            bool needmask = (j0 + 31 > i0);
            #pragma unroll
            for (int rr = 0; rr < 4; ++rr) {
                float v0 = sa0[rr], v1 = sa1[rr];
                if (needmask) {
                    int i = i0 + lg * 4 + rr;
                    if (j0 + lr > i)      v0 = -1e30f;
                    if (j0 + 16 + lr > i) v1 = -1e30f;
                }
                float p0 = __builtin_amdgcn_exp2f(v0);
                float p1 = __builtin_amdgcn_exp2f(v1);
                ssum[rr] += p0 + p1;
                pbuf[w][lg * 4 + rr][lr] = f2bf(p0);
                pbuf[w][lg * 4 + rr][16 + lr] = f2bf(p1);
            }
            short8 pf = *(const short8*)(&pbuf[w][lr][lg * 8]);
            #pragma unroll
            for (int n = 0; n < 8; ++n) {
                int row = n * 16 + lr;
                short8 vf = *(const short8*)(vbp + row * 64 + lg * 16);
                acc[n] = __builtin_amdgcn_mfma_f32_16x16x32_bf16(pf, vf, acc[n], 0, 0, 0);
            }
        }
        if (ti + 1 < size) WRITET(cur ^ 1);
        __syncthreads();
        cur ^= 1;
    }

    unsigned short* dst = accP + (size_t)u * 8 * SLOT_SH + (size_t)w * SLOT_SH;
    #pragma unroll
    for (int n = 0; n < 8; ++n) {
        short4v pv;
        pv[0] = (short)f2bf(acc[n][0]);
        pv[1] = (short)f2bf(acc[n][1]);
        pv[2] = (short)f2bf(acc[n][2]);
        pv[3] = (short)f2bf(acc[n][3]);
        *(short4v*)(dst + n * 256 + lane * 4) = pv;
    }
    #pragma unroll
    for (int rr = 0; rr < 4; ++rr) {
        float s = ssum[rr];
        s += __shfl_xor(s, 1);
        s += __shfl_xor(s, 2);
        s += __shfl_xor(s, 4);
        s += __shfl_xor(s, 8);
        if (lr == 0) ((float*)(dst + 2048))[lg * 4 + rr] = s;
    }
}

// ---------------- Kernel 2b: combine bf16 partials -> out ------------------
__global__ __launch_bounds__(256) void combine3(const unsigned short* __restrict__ accP,
                                                float* __restrict__ out) {
    int cpx = gridDim.x >> 3;
    int bidx = ((int)blockIdx.x & 7) * cpx + ((int)blockIdx.x >> 3);
    int b = bidx >> 7, tile = bidx & 127;          // tile = g*8 + w
    int g = tile >> 3, wq = tile & 7;
    int ub = b * UPB_FA;
    for (int gg = 0; gg < g; ++gg) ub += (4 * gg + 4 + CCHUNK - 1) / CCHUNK;
    int nt = 4 * g + 4;
    int P = (nt + CCHUNK - 1) / CCHUNK;

    int tid = threadIdx.x;
    int row = tid >> 4;
    int c8 = (tid & 15) * 8;

    const unsigned short* base = accP + ((size_t)ub * 8 + wq) * SLOT_SH;
    const size_t pstr = (size_t)8 * SLOT_SH;
    float den = 0.f;
    for (int pp = 0; pp < P; ++pp) den += ((const float*)(base + pp * pstr + 2048))[row];
    float inv = 1.0f / den;

    int lgg = row >> 2, r4 = row & 3;
    float ov[8];
    #pragma unroll
    for (int cc = 0; cc < 8; ++cc) {
        int col = c8 + cc;
        int n = col >> 4, lrr = col & 15;
        int flat = n * 256 + (lgg * 16 + lrr) * 4 + r4;
        float s = 0.f;
        for (int pp = 0; pp < P; ++pp) s += bf2f(base[pp * pstr + flat]);
        ov[cc] = s * inv;
    }
    float* op = out + ((size_t)(b * Tn + tile * 16 + row)) * Hn + c8;
    *(f32x4*)op       = f32x4{ov[0], ov[1], ov[2], ov[3]};
    *(f32x4*)(op + 4) = f32x4{ov[4], ov[5], ov[6], ov[7]};
}

// ---------------- Fallback attention (round-2, in-block kv split) ----------
__global__ __launch_bounds__(256) void attn(const unsigned short* __restrict__ Kb,
                                            const unsigned short* __restrict__ Qb,
                                            const unsigned short* __restrict__ VT,
                                            float* __restrict__ out) {
    __shared__ unsigned short pbuf[4][16][32];
    __shared__ __align__(16) float accbuf[4][16][132];
    __shared__ float ssbuf[4][16];
    int lane = threadIdx.x & 63;
    int w = threadIdx.x >> 6;
    int b = blockIdx.y;
    int xb = blockIdx.x;
    int tile = (xb & 1) ? (127 - (xb >> 1)) : (xb >> 1);
    int i0 = tile * 16;
    int lr = lane & 15, lg = lane >> 4;

    const unsigned short* kb = Kb + (size_t)b * Tn * Hn;
    const unsigned short* qb = Qb + (size_t)b * Tn * Hn;
    const unsigned short* vt = VT + (size_t)b * Hn * Tn;

    short8 kf[4];
    #pragma unroll
    for (int kk = 0; kk < 4; ++kk)
        kf[kk] = *(const short8*)(kb + (size_t)(i0 + lr) * Hn + kk * 32 + lg * 8);

    f32x4 acc[8] = {};
    float ssum[4] = {0.f, 0.f, 0.f, 0.f};

    int nt = (i0 + 15) / 32 + 1;
    for (int tt = w; tt < nt; tt += 4) {
        int j0 = tt * 32;
        f32x4 sa0 = {}, sa1 = {};
        #pragma unroll
        for (int kk = 0; kk < 4; ++kk) {
            short8 q0 = *(const short8*)(qb + (size_t)(j0 + lr) * Hn + kk * 32 + lg * 8);
            sa0 = __builtin_amdgcn_mfma_f32_16x16x32_bf16(kf[kk], q0, sa0, 0, 0, 0);
        }
        #pragma unroll
        for (int kk = 0; kk < 4; ++kk) {
            short8 q1 = *(const short8*)(qb + (size_t)(j0 + 16 + lr) * Hn + kk * 32 + lg * 8);
            sa1 = __builtin_amdgcn_mfma_f32_16x16x32_bf16(kf[kk], q1, sa1, 0, 0, 0);
        }
        bool needmask = (j0 + 31 > i0);
        #pragma unroll
        for (int r = 0; r < 4; ++r) {
            float v0 = sa0[r], v1 = sa1[r];
            if (needmask) {
                int i = i0 + lg * 4 + r;
                if (j0 + lr > i)      v0 = -1e30f;
                if (j0 + 16 + lr > i) v1 = -1e30f;
            }
            float p0 = __builtin_amdgcn_exp2f(v0);
            float p1 = __builtin_amdgcn_exp2f(v1);
            ssum[r] += p0 + p1;
            pbuf[w][lg * 4 + r][lr] = f2bf(p0);
            pbuf[w][lg * 4 + r][16 + lr] = f2bf(p1);
        }
        short8 pf = *(const short8*)(&pbuf[w][lr][lg * 8]);
        #pragma unroll
        for (int n = 0; n < 8; ++n) {
            short8 vf = *(const short8*)(vt + (size_t)(n * 16 + lr) * Tn + j0 + lg * 8);
            acc[n] = __builtin_amdgcn_mfma_f32_16x16x32_bf16(pf, vf, acc[n], 0, 0, 0);
        }
    }

    #pragma unroll
    for (int r = 0; r < 4; ++r) {
        float s = ssum[r];
        s += __shfl_xor(s, 1);
        s += __shfl_xor(s, 2);
        s += __shfl_xor(s, 4);
        s += __shfl_xor(s, 8);
        if (lr == 0) ssbuf[w][lg * 4 + r] = s;
    }
    #pragma unroll
    for (int n = 0; n < 8; ++n)
        #pragma unroll
        for (int r = 0; r < 4; ++r)
            accbuf[w][lg * 4 + r][n * 16 + lr] = acc[n][r];
    __syncthreads();

    int row = threadIdx.x >> 5;
    int col = (threadIdx.x & 31) * 4;
    #pragma unroll
    for (int h = 0; h < 2; ++h) {
        int rr = row + h * 8;
        f32x4 s = *(const f32x4*)(&accbuf[0][rr][col]);
        #pragma unroll
        for (int ww = 1; ww < 4; ++ww) {
            f32x4 t = *(const f32x4*)(&accbuf[ww][rr][col]);
            s[0] += t[0]; s[1] += t[1]; s[2] += t[2]; s[3] += t[3];
        }
        float den = ssbuf[0][rr] + ssbuf[1][rr] + ssbuf[2][rr] + ssbuf[3][rr];
        float inv = 1.0f / den;
        s[0] *= inv; s[1] *= inv; s[2] *= inv; s[3] *= inv;
        *(f32x4*)(&out[((size_t)(b * Tn + i0 + rr)) * Hn + col]) = s;
    }
}

extern "C" void kernel_launch(void* const* d_in, const int* in_sizes, int n_in,
                              void* d_out, int out_size, void* d_ws, size_t ws_size,
                              hipStream_t stream) {
    const float* x  = (const float*)d_in[0];
    const float* Wk = (const float*)d_in[1];
    const float* Wq = (const float*)d_in[2];
    const float* Wv = (const float*)d_in[3];

    unsigned short* Kb = (unsigned short*)d_ws;                 // [8][2048][128] bf16 (pre-scaled)
    unsigned short* Qb = Kb + (size_t)Bn * Tn * Hn;             // [8][2048][128] bf16
    unsigned short* VT = Qb + (size_t)Bn * Tn * Hn;             // [8][128][2048] bf16
    unsigned short* WT = VT + (size_t)Bn * Tn * Hn;             // [3][128][1024] bf16
    unsigned short* accP = (unsigned short*)((char*)d_ws + BASE_BYTES);

    wt_prep<<<dim3(512, 3), 256, 0, stream>>>(Wk, Wq, Wv, WT);
    proj14<<<dim3(256), 512, 0, stream>>>(x, WT, Kb, Qb, VT);

    const size_t need = (size_t)BASE_BYTES + (size_t)NBLK_FA * 8 * SLOT_SH * 2;  // ~32.5 MB
    if (ws_size >= need) {
        fattn8<<<dim3(NBLK_FA), 512, 0, stream>>>(Kb, Qb, VT, accP);
        combine3<<<dim3(1024), 256, 0, stream>>>(accP, (float*)d_out);
    } else {
        attn<<<dim3(128, 8), 256, 0, stream>>>(Kb, Qb, VT, (float*)d_out);
    }
}

// Round 12
// 82.881 us; speedup vs baseline: 2.0588x; 1.0708x over previous
//
#include <hip/hip_runtime.h>
#include <hip/hip_bf16.h>
#include <stdint.h>

#define Bn 8
#define Tn 2048
#define Cn 1024
#define Hn 128

typedef __attribute__((ext_vector_type(8))) short short8;
typedef __attribute__((ext_vector_type(4))) short short4v;
typedef __attribute__((ext_vector_type(4))) float f32x4;
typedef __attribute__((ext_vector_type(4))) int int4v;

static __device__ __forceinline__ unsigned short f2bf(float f) {
    union { float f; unsigned int u; } v; v.f = f;
    return (unsigned short)((v.u + 0x7FFFu + ((v.u >> 16) & 1u)) >> 16);
}
static __device__ __forceinline__ float bf2f(unsigned short h) {
    union { unsigned int u; float f; } v; v.u = ((unsigned int)h) << 16;
    return v.f;
}

// pack 8 f32 -> short8 bf16 (k-ascending), RNE via v_cvt_pk_bf16_f32 (T12/m240)
static __device__ __forceinline__ short8 cvt8(f32x4 a, f32x4 b) {
    union { unsigned int u[4]; short8 s; } r;
    asm("v_cvt_pk_bf16_f32 %0, %1, %2" : "=v"(r.u[0]) : "v"(a[0]), "v"(a[1]));
    asm("v_cvt_pk_bf16_f32 %0, %1, %2" : "=v"(r.u[1]) : "v"(a[2]), "v"(a[3]));
    asm("v_cvt_pk_bf16_f32 %0, %1, %2" : "=v"(r.u[2]) : "v"(b[0]), "v"(b[1]));
    asm("v_cvt_pk_bf16_f32 %0, %1, %2" : "=v"(r.u[3]) : "v"(b[2]), "v"(b[3]));
    return r.s;
}

// async 16B/lane global->LDS (dest = wave-uniform base + lane*16)
static __device__ __forceinline__ void async16(const void* g, void* l) {
    __builtin_amdgcn_global_load_lds(
        (const __attribute__((address_space(1))) unsigned int*)g,
        (__attribute__((address_space(3))) unsigned int*)l,
        16, 0, 0);
}

// K pre-scale: C^-0.5 * log2(e)  (softmax exp computed as exp2)
#define KSCALE 0.04508422f

#define BASE_BYTES (3u * Bn * Tn * Hn * 2u + 3u * Hn * Cn * 2u)   // 13,369,344
// bf16 partial slot: 2048 bf16 acc + 16 f32 ssum = 2080 shorts (4160 B)
#define SLOT_SH 2080
#define NBLK_FA 576   // 8 batches * 72 units
#define UPB_FA 72
#define CCHUNK 8

// ---------------- Kernel 0: W [1024][128] f32 -> WT [3][128][1024] bf16 ----
__global__ __launch_bounds__(256) void wt_prep(const float* __restrict__ Wk,
                                               const float* __restrict__ Wq,
                                               const float* __restrict__ Wv,
                                               unsigned short* __restrict__ WT) {
    int z = blockIdx.y;
    const float* W = (z == 0) ? Wk : (z == 1) ? Wq : Wv;
    unsigned short* wt = WT + (size_t)z * Hn * Cn;
    int o = blockIdx.x * 256 + threadIdx.x;
    int d = o >> 10;
    int k = o & (Cn - 1);
    wt[o] = f2bf(W[k * Hn + d]);
}

// ---------------- Kernel 1: fused K/Q/V projection, BK=32, depth-2 --------
// Session-best ground-truth configuration (round 4, 83.0us total).
// grid 768 = 256 row-groups x 3 z (K/Q/V). Block: 64 rows x 128 cols, BK=32,
// 4 waves (2M x 2N), 16 MFMA/step, 32 K-steps. ALL staging via
// global_load_lds (A raw f32, cvt at read; B bf16 with pre-swizzled source).
// Triple-buffer, STAGE issued 2 steps ahead; raw s_barrier + counted
// vmcnt(4). LDS 48KB -> 3 blocks/CU (the occupancy that sets the ~9 TB/s
// staging service rate -- r7 ablation showed staging is 100% of runtime).
__global__ __launch_bounds__(256) void proj9(const float* __restrict__ x,
                                             const unsigned short* __restrict__ WTb,
                                             unsigned short* __restrict__ Kb,
                                             unsigned short* __restrict__ Qb,
                                             unsigned short* __restrict__ VT) {
    __shared__ __align__(16) unsigned short Bsm[3][128 * 32];  // 8KB/buf, slot^((row>>1)&3)
    __shared__ __align__(16) float Asm[3][64 * 32];            // 8KB/buf, slot^(row&7)
    int tid = threadIdx.x;
    int lane = tid & 63, w = tid >> 6;
    int lr = lane & 15, lg = lane >> 4;
    int wm = w >> 1, wn = w & 1;

    // XCD-chunked swizzle (768 % 8 == 0): the 3 cg-blocks of a row-group land
    // on the same XCD adjacent in time -> x slice is L2-hit for 2 of 3 reads.
    int u = ((int)(blockIdx.x & 7)) * 96 + ((int)blockIdx.x >> 3);
    int rg = u / 3, cg = u - rg * 3;
    int r0 = rg * 64;
    const unsigned short* WTz = WTb + (size_t)cg * Hn * Cn;

    // B: 8 chunks/buf (1KB = 16 rows x 64B); wave w stages chunks 2w,2w+1.
    // A: 8 chunks/buf (1KB = 8 rows x 128B); wave w stages chunks 2w,2w+1.
    // LDS dest linear; global source slot pre-swizzled (rule #21 involution).
    const unsigned short* bsrc[2];
    const float* asrc[2];
    #pragma unroll
    for (int i = 0; i < 2; ++i) {
        int ch = w * 2 + i;
        int brow = ch * 16 + (lane >> 2);
        int bslot = (lane & 3) ^ ((brow >> 1) & 3);
        bsrc[i] = WTz + (size_t)brow * Cn + bslot * 8;
        int arow = ch * 8 + (lane >> 3);
        int aslot = (lane & 7) ^ (arow & 7);
        asrc[i] = x + (size_t)(r0 + arow) * Cn + aslot * 4;
    }

    auto STAGE = [&](int bb, int k0) {   // 4 vm ops per wave
        #pragma unroll
        for (int i = 0; i < 2; ++i) {
            int ch = w * 2 + i;
            async16(bsrc[i] + k0, &Bsm[bb][ch * 512]);
            async16(asrc[i] + k0, &Asm[bb][ch * 256]);
        }
    };

    f32x4 acc[2][4] = {};
    STAGE(0, 0);
    STAGE(1, 32);
    int cur = 0;
    for (int ks = 0; ks < 32; ++ks) {
        // outstanding here: STAGE(ks) [oldest 4] + STAGE(ks+1) [newest 4].
        // Keep the newest 4 in flight; full drain only on the last step.
        if (ks < 31) asm volatile("s_waitcnt vmcnt(4)" ::: "memory");
        else         asm volatile("s_waitcnt vmcnt(0)" ::: "memory");
        __builtin_amdgcn_s_barrier();
        __builtin_amdgcn_sched_barrier(0);
        if (ks < 30) {
            int nb = cur + 2; if (nb >= 3) nb -= 3;
            STAGE(nb, (ks + 2) * 32);
        }
        const char* ab = (const char*)&Asm[cur][0];
        const char* bbp = (const char*)&Bsm[cur][0];
        short8 af[2], bf[4];
        #pragma unroll
        for (int m = 0; m < 2; ++m) {
            int row = wm * 32 + m * 16 + lr;
            const char* abase = ab + row * 128;
            f32x4 a0 = *(const f32x4*)(abase + (((lg * 2)     ^ (row & 7)) << 4));
            f32x4 a1 = *(const f32x4*)(abase + (((lg * 2 + 1) ^ (row & 7)) << 4));
            af[m] = cvt8(a0, a1);
        }
        #pragma unroll
        for (int c = 0; c < 4; ++c) {
            int row = wn * 64 + c * 16 + lr;
            bf[c] = *(const short8*)(bbp + row * 64 + ((lg ^ ((row >> 1) & 3)) << 4));
        }
        #pragma unroll
        for (int m = 0; m < 2; ++m)
            #pragma unroll
            for (int c = 0; c < 4; ++c)
                acc[m][c] = __builtin_amdgcn_mfma_f32_16x16x32_bf16(af[m], bf[c], acc[m][c], 0, 0, 0);
        ++cur; if (cur == 3) cur = 0;
    }

    if (cg == 2) {
        // V: transposed store VT[b][d][t], 4 consecutive t per short4v
        int bb = r0 >> 11;
        int tb = r0 & 2047;
        #pragma unroll
        for (int m = 0; m < 2; ++m)
            #pragma unroll
            for (int c = 0; c < 4; ++c) {
                int d = wn * 64 + c * 16 + lr;
                int t = tb + wm * 32 + m * 16 + lg * 4;
                short4v pv;
                pv[0] = (short)f2bf(acc[m][c][0]);
                pv[1] = (short)f2bf(acc[m][c][1]);
                pv[2] = (short)f2bf(acc[m][c][2]);
                pv[3] = (short)f2bf(acc[m][c][3]);
                *(short4v*)(VT + ((size_t)(bb * Hn + d) << 11) + t) = pv;
            }
    } else {
        unsigned short* outp = (cg == 0) ? Kb : Qb;
        float sc = (cg == 0) ? KSCALE : 1.0f;
        #pragma unroll
        for (int m = 0; m < 2; ++m)
            #pragma unroll
            for (int c = 0; c < 4; ++c) {
                int d = wn * 64 + c * 16 + lr;
                #pragma unroll
                for (int r = 0; r < 4; ++r) {
                    int i = r0 + wm * 32 + m * 16 + lg * 4 + r;
                    outp[(size_t)i * Hn + d] = f2bf(acc[m][c][r] * sc);
                }
            }
    }
}

// ---------------- Kernel 2a: attention partials (8-wave shared-kv) ---------
// Block = (b, 128-row group g of 16, chunk p of <=8 kv-tiles). 512 threads:
// wave w owns q-tile g*8+w (16 rows). kv-tiles staged once, shared by 8 waves
// (r10 proved the 8x LDS reuse is load-bearing: de-staging was 30->114us).
__global__ __launch_bounds__(512) void fattn8(const unsigned short* __restrict__ Kb,
                                              const unsigned short* __restrict__ Qb,
                                              const unsigned short* __restrict__ VT,
                                              unsigned short* __restrict__ accP) {
    __shared__ __align__(16) unsigned short Ksm[2][32 * 128];   // kv rows x d, swz (row&7)<<4
    __shared__ __align__(16) unsigned short Vsm[2][128 * 32];   // d rows x t, dense
    __shared__ __align__(16) unsigned short pbuf[8][16][48];
    int tid = threadIdx.x, lane = tid & 63, w = tid >> 6;
    int lr = lane & 15, lg = lane >> 4;

    // batch-contiguous XCD swizzle: XCD i -> units of batch i (L2-resident)
    int cpx = gridDim.x >> 3;
    int u = ((int)blockIdx.x & 7) * cpx + ((int)blockIdx.x >> 3);
    int b = u / UPB_FA, rem = u - b * UPB_FA;
    int g = 0, p = 0;
    for (;;) {
        int P = (4 * g + 4 + CCHUNK - 1) / CCHUNK;
        if (rem < P) { p = rem; break; }
        rem -= P; ++g;
    }
    int nt = 4 * g + 4;
    int P = (nt + CCHUNK - 1) / CCHUNK;
    int q = nt / P, r = nt % P;
    int begin = p * q + (p < r ? p : r);
    int size = q + (p < r ? 1 : 0);

    int i0 = g * 128 + w * 16;
    int tmax = (i0 + 15) >> 5;
    const unsigned short* kb = Kb + (size_t)b * Tn * Hn;
    const unsigned short* qb = Qb + (size_t)b * Tn * Hn;
    const unsigned short* vt = VT + (size_t)b * Hn * Tn;

    short8 kf[4];
    #pragma unroll
    for (int kk = 0; kk < 4; ++kk)
        kf[kk] = *(const short8*)(kb + (size_t)(i0 + lr) * Hn + kk * 32 + lg * 8);

    int krow = tid >> 4, kcol = (tid & 15) * 8;    // K stage: 32 rows x 128 d
    int vrow = tid >> 2, vcol = (tid & 3) * 8;     // V stage: 128 rows x 32 t
    int4v kreg, vreg;
    auto LOADT = [&](int tt) {
        int j0 = tt * 32;
        kreg = *(const int4v*)(qb + (size_t)(j0 + krow) * Hn + kcol);
        vreg = *(const int4v*)(vt + (size_t)vrow * Tn + j0 + vcol);
    };
    auto WRITET = [&](int bb) {
        *(int4v*)((char*)&Ksm[bb][0] + krow * 256 + ((kcol * 2) ^ ((krow & 7) << 4))) = kreg;
        *(int4v*)((char*)&Vsm[bb][0] + vrow * 64 + vcol * 2) = vreg;
    };

    f32x4 acc[8] = {};
    float ssum[4] = {0.f, 0.f, 0.f, 0.f};

    LOADT(begin);
    WRITET(0);
    __syncthreads();
    int cur = 0;
    for (int ti = 0; ti < size; ++ti) {
        int tt = begin + ti;
        if (ti + 1 < size) LOADT(tt + 1);
        if (tt <= tmax) {
            int j0 = tt * 32;
            const char* kbp = (const char*)&Ksm[cur][0];
            const char* vbp = (const char*)&Vsm[cur][0];
            f32x4 sa0 = {}, sa1 = {};
            #pragma unroll
            for (int kk = 0; kk < 4; ++kk) {
                int row = lr;
                short8 qf = *(const short8*)(kbp + row * 256 + (((kk * 64) + lg * 16) ^ ((row & 7) << 4)));
                sa0 = __builtin_amdgcn_mfma_f32_16x16x32_bf16(kf[kk], qf, sa0, 0, 0, 0);
            }
            #pragma unroll
            for (int kk = 0; kk < 4; ++kk) {
                int row = 16 + lr;
                short8 qf = *(const short8*)(kbp + row * 256 + (((kk * 64) + lg * 16) ^ ((row & 7) << 4)));
                sa1 = __builtin_amdgcn_mfma_f32_16x16x32_bf16(kf[kk], qf, sa1, 0, 0, 0);
            }
            bool needmask = (j0 + 31 > i0);
            #pragma unroll
            for (int rr = 0; rr < 4; ++rr) {
                float v0 = sa0[rr], v1 = sa1[rr];
                if (needmask) {
                    int i = i0 + lg * 4 + rr;
                    if (j0 + lr > i)      v0 = -1e30f;
                    if (j0 + 16 + lr > i) v1 = -1e30f;
                }
                float p0 = __builtin_amdgcn_exp2f(v0);
                float p1 = __builtin_amdgcn_exp2f(v1);
                ssum[rr] += p0 + p1;
                pbuf[w][lg * 4 + rr][lr] = f2bf(p0);
                pbuf[w][lg * 4 + rr][16 + lr] = f2bf(p1);
            }
            short8 pf = *(const short8*)(&pbuf[w][lr][lg * 8]);
            #pragma unroll
            for (int n = 0; n < 8; ++n) {
                int row = n * 16 + lr;
                short8 vf = *(const short8*)(vbp + row * 64 + lg * 16);
                acc[n] = __builtin_amdgcn_mfma_f32_16x16x32_bf16(pf, vf, acc[n], 0, 0, 0);
            }
        }
        if (ti + 1 < size) WRITET(cur ^ 1);
        __syncthreads();
        cur ^= 1;
    }

    // store bf16 partial (reg-native layout), 8B/lane per n
    unsigned short* dst = accP + (size_t)u * 8 * SLOT_SH + (size_t)w * SLOT_SH;
    #pragma unroll
    for (int n = 0; n < 8; ++n) {
        short4v pv;
        pv[0] = (short)f2bf(acc[n][0]);
        pv[1] = (short)f2bf(acc[n][1]);
        pv[2] = (short)f2bf(acc[n][2]);
        pv[3] = (short)f2bf(acc[n][3]);
        *(short4v*)(dst + n * 256 + lane * 4) = pv;
    }
    #pragma unroll
    for (int rr = 0; rr < 4; ++rr) {
        float s = ssum[rr];
        s += __shfl_xor(s, 1);
        s += __shfl_xor(s, 2);
        s += __shfl_xor(s, 4);
        s += __shfl_xor(s, 8);
        if (lr == 0) ((float*)(dst + 2048))[lg * 4 + rr] = s;
    }
}

// ---------------- Kernel 2b: combine bf16 partials -> out ------------------
__global__ __launch_bounds__(256) void combine3(const unsigned short* __restrict__ accP,
                                                float* __restrict__ out) {
    int cpx = gridDim.x >> 3;
    int bidx = ((int)blockIdx.x & 7) * cpx + ((int)blockIdx.x >> 3);
    int b = bidx >> 7, tile = bidx & 127;          // tile = g*8 + w
    int g = tile >> 3, wq = tile & 7;
    int ub = b * UPB_FA;
    for (int gg = 0; gg < g; ++gg) ub += (4 * gg + 4 + CCHUNK - 1) / CCHUNK;
    int nt = 4 * g + 4;
    int P = (nt + CCHUNK - 1) / CCHUNK;

    int tid = threadIdx.x;
    int row = tid >> 4;
    int c8 = (tid & 15) * 8;

    const unsigned short* base = accP + ((size_t)ub * 8 + wq) * SLOT_SH;
    const size_t pstr = (size_t)8 * SLOT_SH;
    float den = 0.f;
    for (int pp = 0; pp < P; ++pp) den += ((const float*)(base + pp * pstr + 2048))[row];
    float inv = 1.0f / den;

    int lgg = row >> 2, r4 = row & 3;
    float ov[8];
    #pragma unroll
    for (int cc = 0; cc < 8; ++cc) {
        int col = c8 + cc;
        int n = col >> 4, lrr = col & 15;
        int flat = n * 256 + (lgg * 16 + lrr) * 4 + r4;
        float s = 0.f;
        for (int pp = 0; pp < P; ++pp) s += bf2f(base[pp * pstr + flat]);
        ov[cc] = s * inv;
    }
    float* op = out + ((size_t)(b * Tn + tile * 16 + row)) * Hn + c8;
    *(f32x4*)op       = f32x4{ov[0], ov[1], ov[2], ov[3]};
    *(f32x4*)(op + 4) = f32x4{ov[4], ov[5], ov[6], ov[7]};
}

// ---------------- Fallback attention (round-2, in-block kv split) ----------
__global__ __launch_bounds__(256) void attn(const unsigned short* __restrict__ Kb,
                                            const unsigned short* __restrict__ Qb,
                                            const unsigned short* __restrict__ VT,
                                            float* __restrict__ out) {
    __shared__ unsigned short pbuf[4][16][32];
    __shared__ __align__(16) float accbuf[4][16][132];
    __shared__ float ssbuf[4][16];
    int lane = threadIdx.x & 63;
    int w = threadIdx.x >> 6;
    int b = blockIdx.y;
    int xb = blockIdx.x;
    int tile = (xb & 1) ? (127 - (xb >> 1)) : (xb >> 1);
    int i0 = tile * 16;
    int lr = lane & 15, lg = lane >> 4;

    const unsigned short* kb = Kb + (size_t)b * Tn * Hn;
    const unsigned short* qb = Qb + (size_t)b * Tn * Hn;
    const unsigned short* vt = VT + (size_t)b * Hn * Tn;

    short8 kf[4];
    #pragma unroll
    for (int kk = 0; kk < 4; ++kk)
        kf[kk] = *(const short8*)(kb + (size_t)(i0 + lr) * Hn + kk * 32 + lg * 8);

    f32x4 acc[8] = {};
    float ssum[4] = {0.f, 0.f, 0.f, 0.f};

    int nt = (i0 + 15) / 32 + 1;
    for (int tt = w; tt < nt; tt += 4) {
        int j0 = tt * 32;
        f32x4 sa0 = {}, sa1 = {};
        #pragma unroll
        for (int kk = 0; kk < 4; ++kk) {
            short8 q0 = *(const short8*)(qb + (size_t)(j0 + lr) * Hn + kk * 32 + lg * 8);
            sa0 = __builtin_amdgcn_mfma_f32_16x16x32_bf16(kf[kk], q0, sa0, 0, 0, 0);
        }
        #pragma unroll
        for (int kk = 0; kk < 4; ++kk) {
            short8 q1 = *(const short8*)(qb + (size_t)(j0 + 16 + lr) * Hn + kk * 32 + lg * 8);
            sa1 = __builtin_amdgcn_mfma_f32_16x16x32_bf16(kf[kk], q1, sa1, 0, 0, 0);
        }
        bool needmask = (j0 + 31 > i0);
        #pragma unroll
        for (int r = 0; r < 4; ++r) {
            float v0 = sa0[r], v1 = sa1[r];
            if (needmask) {
                int i = i0 + lg * 4 + r;
                if (j0 + lr > i)      v0 = -1e30f;
                if (j0 + 16 + lr > i) v1 = -1e30f;
            }
            float p0 = __builtin_amdgcn_exp2f(v0);
            float p1 = __builtin_amdgcn_exp2f(v1);
            ssum[r] += p0 + p1;
            pbuf[w][lg * 4 + r][lr] = f2bf(p0);
            pbuf[w][lg * 4 + r][16 + lr] = f2bf(p1);
        }
        short8 pf = *(const short8*)(&pbuf[w][lr][lg * 8]);
        #pragma unroll
        for (int n = 0; n < 8; ++n) {
            short8 vf = *(const short8*)(vt + (size_t)(n * 16 + lr) * Tn + j0 + lg * 8);
            acc[n] = __builtin_amdgcn_mfma_f32_16x16x32_bf16(pf, vf, acc[n], 0, 0, 0);
        }
    }

    #pragma unroll
    for (int r = 0; r < 4; ++r) {
        float s = ssum[r];
        s += __shfl_xor(s, 1);
        s += __shfl_xor(s, 2);
        s += __shfl_xor(s, 4);
        s += __shfl_xor(s, 8);
        if (lr == 0) ssbuf[w][lg * 4 + r] = s;
    }
    #pragma unroll
    for (int n = 0; n < 8; ++n)
        #pragma unroll
        for (int r = 0; r < 4; ++r)
            accbuf[w][lg * 4 + r][n * 16 + lr] = acc[n][r];
    __syncthreads();

    int row = threadIdx.x >> 5;
    int col = (threadIdx.x & 31) * 4;
    #pragma unroll
    for (int h = 0; h < 2; ++h) {
        int rr = row + h * 8;
        f32x4 s = *(const f32x4*)(&accbuf[0][rr][col]);
        #pragma unroll
        for (int ww = 1; ww < 4; ++ww) {
            f32x4 t = *(const f32x4*)(&accbuf[ww][rr][col]);
            s[0] += t[0]; s[1] += t[1]; s[2] += t[2]; s[3] += t[3];
        }
        float den = ssbuf[0][rr] + ssbuf[1][rr] + ssbuf[2][rr] + ssbuf[3][rr];
        float inv = 1.0f / den;
        s[0] *= inv; s[1] *= inv; s[2] *= inv; s[3] *= inv;
        *(f32x4*)(&out[((size_t)(b * Tn + i0 + rr)) * Hn + col]) = s;
    }
}

extern "C" void kernel_launch(void* const* d_in, const int* in_sizes, int n_in,
                              void* d_out, int out_size, void* d_ws, size_t ws_size,
                              hipStream_t stream) {
    const float* x  = (const float*)d_in[0];
    const float* Wk = (const float*)d_in[1];
    const float* Wq = (const float*)d_in[2];
    const float* Wv = (const float*)d_in[3];

    unsigned short* Kb = (unsigned short*)d_ws;                 // [8][2048][128] bf16 (pre-scaled)
    unsigned short* Qb = Kb + (size_t)Bn * Tn * Hn;             // [8][2048][128] bf16
    unsigned short* VT = Qb + (size_t)Bn * Tn * Hn;             // [8][128][2048] bf16
    unsigned short* WT = VT + (size_t)Bn * Tn * Hn;             // [3][128][1024] bf16
    unsigned short* accP = (unsigned short*)((char*)d_ws + BASE_BYTES);

    wt_prep<<<dim3(512, 3), 256, 0, stream>>>(Wk, Wq, Wv, WT);
    proj9<<<dim3(768), 256, 0, stream>>>(x, WT, Kb, Qb, VT);

    const size_t need = (size_t)BASE_BYTES + (size_t)NBLK_FA * 8 * SLOT_SH * 2;  // ~32.5 MB
    if (ws_size >= need) {
        fattn8<<<dim3(NBLK_FA), 512, 0, stream>>>(Kb, Qb, VT, accP);
        combine3<<<dim3(1024), 256, 0, stream>>>(accP, (float*)d_out);
    } else {
        attn<<<dim3(128, 8), 256, 0, stream>>>(Kb, Qb, VT, (float*)d_out);
    }
}